// Round 3
// baseline (174.217 us; speedup 1.0000x reference)
//
#include <hip/hip_runtime.h>

#define DEV __device__ __forceinline__

typedef unsigned short u16;
typedef __attribute__((ext_vector_type(8))) short bf16x8;   // 8 bf16 (4 VGPRs)
typedef __attribute__((ext_vector_type(8))) unsigned short u16x8;
typedef __attribute__((ext_vector_type(4))) float f32x4;

constexpr int Bz = 32, Lz = 1024, Dz = 384, Fz = 384, KWz = 3, Mz = 4096;
constexpr float EPS = 1e-5f;

DEV u16 f2bf(float f) {  // RNE f32 -> bf16
  unsigned u = __float_as_uint(f);
  u += 0x7fffu + ((u >> 16) & 1u);
  return (u16)(u >> 16);
}

typedef __attribute__((address_space(1))) const unsigned char ga_t;
typedef __attribute__((address_space(3))) unsigned char la_t;
DEV void gload16(const void* g, void* l) {
  // async global->LDS, 16B per lane; LDS dest is wave-uniform base + lane*16
  __builtin_amdgcn_global_load_lds((ga_t*)g, (la_t*)l, 16, 0, 0);
}

// ---- fused: convert x (f32 -> padded bf16 [B][L+2][D]) + weight prep -------
__global__ void k_pre(const float* __restrict__ x, u16* __restrict__ xbf,
                      const float* __restrict__ w1, const float* __restrict__ w2,
                      u16* __restrict__ w1t, u16* __restrict__ w2t,
                      u16* __restrict__ h1) {
  constexpr int CONV_BLKS = (Bz * Lz * Dz / 8) / 256;  // 768
  if (blockIdx.x < CONV_BLKS) {
    int gid = blockIdx.x * 256 + threadIdx.x;
    size_t e = (size_t)gid * 8;
    float4 v0 = *reinterpret_cast<const float4*>(x + e);
    float4 v1 = *reinterpret_cast<const float4*>(x + e + 4);
    int d = (int)(e % Dz);               // 8 | 384 -> never crosses a row
    int l = (int)((e / Dz) % Lz);
    int b = (int)(e / ((size_t)Dz * Lz));
    u16x8 u;
    u[0] = f2bf(v0.x); u[1] = f2bf(v0.y); u[2] = f2bf(v0.z); u[3] = f2bf(v0.w);
    u[4] = f2bf(v1.x); u[5] = f2bf(v1.y); u[6] = f2bf(v1.z); u[7] = f2bf(v1.w);
    *reinterpret_cast<u16x8*>(xbf + ((size_t)(b * (Lz + 2) + l + 1)) * Dz + d) = u;
    return;
  }
  int gid = (blockIdx.x - CONV_BLKS) * 256 + threadIdx.x;
  constexpr int WT = KWz * Fz * Dz;  // 442368
  if (gid < WT) {
    int k = gid / (Fz * Dz), rem = gid % (Fz * Dz);
    int f = rem / Dz, d = rem % Dz;
    w1t[gid] = f2bf(w1[(f * Dz + d) * KWz + k]);
  } else if (gid < 2 * WT) {
    int g2 = gid - WT;
    int k = g2 / (Fz * Fz), rem = g2 % (Fz * Fz);
    int co = rem / Fz, ci = rem % Fz;
    w2t[g2] = f2bf(w2[(co * Fz + ci) * KWz + k]);
  } else {
    int p = gid - 2 * WT;
    if (p < 2 * Bz * 2 * Dz) {  // halo rows of xbf and h1
      u16* buf = (p < Bz * 2 * Dz) ? xbf : h1;
      int q = p % (Bz * 2 * Dz);
      int b = q / (2 * Dz), r = (q / Dz) & 1, d = q % Dz;
      size_t row = (size_t)b * (Lz + 2) + (r ? (Lz + 1) : 0);
      buf[row * Dz + d] = 0;
    }
  }
}

// -------- cumsum of durations + searchsorted(right) -> idx per frame --------
__global__ __launch_bounds__(1024) void k_scan(const int* __restrict__ tgt,
                                               int* __restrict__ idxb) {
  __shared__ int sc[Lz];
  int b = blockIdx.x, tid = threadIdx.x;
  sc[tid] = tgt[b * Lz + tid];
  __syncthreads();
  for (int off = 1; off < Lz; off <<= 1) {
    int add = (tid >= off) ? sc[tid - off] : 0;
    __syncthreads();
    sc[tid] += add;
    __syncthreads();
  }
  int total = sc[Lz - 1];
  for (int t = tid; t < Mz; t += 1024) {
    int lo = 0, hi = Lz;
    while (lo < hi) {  // first j with cum[j] > t  (== searchsorted right)
      int mid = (lo + hi) >> 1;
      if (sc[mid] > t) hi = mid; else lo = mid + 1;
    }
    int iv = (t < total) ? (lo > Lz - 1 ? Lz - 1 : lo) : -1;
    idxb[b * Mz + t] = iv;
  }
}

// ------------------------------ gather rows ---------------------------------
__global__ void k_gather(const float* __restrict__ x, const int* __restrict__ idxb,
                         float* __restrict__ out) {
  int wid = (blockIdx.x * blockDim.x + threadIdx.x) >> 6;
  int lane = threadIdx.x & 63;
  int nw = (gridDim.x * blockDim.x) >> 6;
  for (int row = wid; row < Bz * Mz; row += nw) {
    int b = row >> 12;  // Mz = 4096
    int iv = idxb[row];
    float4* dst = reinterpret_cast<float4*>(out + (size_t)row * Dz);
    if (iv < 0) {
      float4 z = make_float4(0.f, 0.f, 0.f, 0.f);
      dst[lane] = z;
      if (lane < 32) dst[64 + lane] = z;
    } else {
      const float4* src =
          reinterpret_cast<const float4*>(x + ((size_t)b * Lz + iv) * Dz);
      dst[lane] = src[lane];
      if (lane < 32) dst[64 + lane] = src[64 + lane];
    }
  }
}

// --------- fused conv1d(K=3,'same') + LayerNorm + ReLU (+ final dot) --------
// GEMM tile: [64 rows] x [384 cols], K = 3 taps * 384. 8 waves (1x8), wave
// 64x48. 2-phase double-buffer; 62KB LDS + <=128 VGPR -> 2 blocks/CU so
// inter-block overlap hides the per-barrier vmcnt drain (m114).
template <int LAYER>
__global__ __launch_bounds__(512, 4) void k_conv(
    const u16* __restrict__ in,    // [Bz][Lz+2][384] bf16 (halo-padded)
    const u16* __restrict__ wt,    // [3][384 out][384 in] bf16
    const float* __restrict__ cbias,
    const float* __restrict__ lng, const float* __restrict__ lnb,
    u16* __restrict__ hout,        // LAYER==1: padded output buffer
    const float* __restrict__ lw, const float* __restrict__ lbias,
    float* __restrict__ dur)       // LAYER==2: [B*L]
{
  __shared__ __align__(16) u16 Ash[2][64 * 32];    // 2 x 4KB
  __shared__ __align__(16) u16 Bsh[2][384 * 32];   // 2 x 24KB
  __shared__ float s_sum[8][64], s_sq[8][64], s_dot[8][64];

  const int tid = threadIdx.x;
  const int lane = tid & 63, wave = tid >> 6;
  const int wc = wave;                         // 1 x 8 wave grid
  const int l15 = lane & 15, lh = lane >> 4;
  const int blk = blockIdx.x;
  const int b = blk >> 4, l0 = (blk & 15) << 6;

  // ---- staging: 28 chunks of 1KB (A:0-3, B:4-27), wave w takes w, w+8, ... -
  const u16* in_row = in + ((size_t)(b * (Lz + 2) + l0)) * 384;
  int gof[4], ldo[4];
  bool isa[4]; int nch = 0;
  #pragma unroll 4
  for (int i = 0; i < 4; ++i) {
    int c = wave + i * 8;
    if (c < 28) {
      bool a = (c < 4);
      int cb = a ? c : c - 4;
      int slot = cb * 64 + lane, r = slot >> 2, q = slot & 3;
      int ks = q ^ ((r >> 1) & 3);           // XOR slot swizzle (involution)
      gof[i] = r * 384 + ks * 8;
      ldo[i] = cb * 512;
      isa[i] = a;
      nch = i + 1;
    }
  }

  auto STAGE = [&](int kt, int buf) {
    int tap = kt / 12;
    int d0 = (kt - tap * 12) * 32;
    const u16* sa = in_row + tap * 384 + d0;
    const u16* sb = wt + tap * (384 * 384) + d0;
    #pragma unroll 4
    for (int i = 0; i < 4; ++i) {
      if (i < nch) {
        if (isa[i]) gload16(sa + gof[i], &Ash[buf][ldo[i]]);
        else        gload16(sb + gof[i], &Bsh[buf][ldo[i]]);
      }
    }
  };

  // ---- fragment read offsets (u16 units), swizzle ks = lh ^ ((r>>1)&3) ----
  int aoff[4], boff[3];
  #pragma unroll
  for (int m = 0; m < 4; ++m) {
    int r = m * 16 + l15;
    aoff[m] = r * 32 + (lh ^ ((r >> 1) & 3)) * 8;
  }
  #pragma unroll
  for (int n = 0; n < 3; ++n) {
    int c = wc * 48 + n * 16 + l15;
    boff[n] = c * 32 + (lh ^ ((c >> 1) & 3)) * 8;
  }

  f32x4 acc[4][3] = {};

  STAGE(0, 0);
  __syncthreads();
  for (int kt = 0; kt < 36; ++kt) {
    const int buf = kt & 1;
    if (kt < 35) STAGE(kt + 1, buf ^ 1);
    bf16x8 av[4], bv[3];
    #pragma unroll
    for (int m = 0; m < 4; ++m)
      av[m] = *reinterpret_cast<const bf16x8*>(&Ash[buf][aoff[m]]);
    #pragma unroll
    for (int n = 0; n < 3; ++n)
      bv[n] = *reinterpret_cast<const bf16x8*>(&Bsh[buf][boff[n]]);
    #pragma unroll
    for (int m = 0; m < 4; ++m)
      #pragma unroll
      for (int n = 0; n < 3; ++n)
        acc[m][n] =
            __builtin_amdgcn_mfma_f32_16x16x32_bf16(av[m], bv[n], acc[m][n], 0, 0, 0);
    __syncthreads();  // drains vmcnt(0); other resident block covers the gap
  }

  // ---- epilogue: bias + LayerNorm(F) + ReLU, then store bf16 or dot(lw) ----
  float gv[3], bvv[3], cbv[3], lwv[3];
  #pragma unroll
  for (int n = 0; n < 3; ++n) {
    int c = wc * 48 + n * 16 + l15;
    gv[n] = lng[c]; bvv[n] = lnb[c]; cbv[n] = cbias[c];
    lwv[n] = (LAYER == 2) ? lw[c] : 0.f;
  }
  #pragma unroll
  for (int m = 0; m < 4; ++m) {
    #pragma unroll
    for (int r = 0; r < 4; ++r) {
      float s = 0.f, q2 = 0.f;
      #pragma unroll
      for (int n = 0; n < 3; ++n) {
        float v = acc[m][n][r] + cbv[n];
        s += v; q2 += v * v;
      }
      #pragma unroll
      for (int off = 1; off < 16; off <<= 1) {
        s += __shfl_xor(s, off);
        q2 += __shfl_xor(q2, off);
      }
      if (l15 == 0) {
        int row = m * 16 + lh * 4 + r;
        s_sum[wc][row] = s;
        s_sq[wc][row] = q2;
      }
    }
  }
  __syncthreads();
  #pragma unroll
  for (int m = 0; m < 4; ++m) {
    #pragma unroll
    for (int r = 0; r < 4; ++r) {
      int row = m * 16 + lh * 4 + r;
      float S = 0.f, Q = 0.f;
      #pragma unroll
      for (int w = 0; w < 8; ++w) { S += s_sum[w][row]; Q += s_sq[w][row]; }
      float mean = S * (1.f / 384.f);
      float var = Q * (1.f / 384.f) - mean * mean;
      float rstd = rsqrtf(var + EPS);
      float dotp = 0.f;
      #pragma unroll
      for (int n = 0; n < 3; ++n) {
        float v = acc[m][n][r] + cbv[n];
        float y = fmaxf((v - mean) * rstd * gv[n] + bvv[n], 0.f);
        if constexpr (LAYER == 1) {
          int c = wc * 48 + n * 16 + l15;
          hout[((size_t)(b * (Lz + 2) + l0 + row + 1)) * 384 + c] = f2bf(y);
        } else {
          dotp += y * lwv[n];
        }
      }
      if constexpr (LAYER == 2) {
        #pragma unroll
        for (int off = 1; off < 16; off <<= 1) dotp += __shfl_xor(dotp, off);
        if (l15 == 0) s_dot[wc][row] = dotp;
      }
    }
  }
  if constexpr (LAYER == 2) {
    __syncthreads();
    if (tid < 64) {
      float dsum = lbias[0];
      #pragma unroll
      for (int w = 0; w < 8; ++w) dsum += s_dot[w][tid];
      dur[(size_t)b * Lz + l0 + tid] = fmaxf(dsum, 0.f);
    }
  }
}

extern "C" void kernel_launch(void* const* d_in, const int* in_sizes, int n_in,
                              void* d_out, int out_size, void* d_ws, size_t ws_size,
                              hipStream_t stream) {
  (void)in_sizes; (void)n_in; (void)out_size; (void)ws_size;
  const float* x   = (const float*)d_in[0];
  const int* tgt   = (const int*)d_in[1];
  const float* w1  = (const float*)d_in[3];
  const float* c1b = (const float*)d_in[4];
  const float* g1  = (const float*)d_in[5];
  const float* b1  = (const float*)d_in[6];
  const float* w2  = (const float*)d_in[7];
  const float* c2b = (const float*)d_in[8];
  const float* g2  = (const float*)d_in[9];
  const float* b2  = (const float*)d_in[10];
  const float* lw  = (const float*)d_in[11];
  const float* lb  = (const float*)d_in[12];

  float* out0 = (float*)d_out;
  float* dur  = out0 + (size_t)Bz * Mz * Dz;

  const size_t xbf_n = (size_t)Bz * (Lz + 2) * Dz;  // 12,607,488 bf16
  const size_t wt_n  = (size_t)KWz * Fz * Dz;       // 442,368 bf16
  u16* xbf = (u16*)d_ws;
  u16* h1  = xbf + xbf_n;
  u16* w1t = h1 + xbf_n;
  u16* w2t = w1t + wt_n;
  int* idxb = (int*)(w2t + wt_n);  // byte offset divisible by 4

  constexpr int CONV_BLKS = (Bz * Lz * Dz / 8) / 256;           // 768
  constexpr int PREP_BLKS = (2 * KWz * Fz * Dz + 2 * Bz * 2 * Dz + 255) / 256;
  k_pre<<<CONV_BLKS + PREP_BLKS, 256, 0, stream>>>(x, xbf, w1, w2, w1t, w2t, h1);
  k_scan<<<Bz, 1024, 0, stream>>>(tgt, idxb);
  k_conv<1><<<512, 512, 0, stream>>>(xbf, w1t, c1b, g1, b1, h1, nullptr, nullptr,
                                     nullptr);
  k_conv<2><<<512, 512, 0, stream>>>(h1, w2t, c2b, g2, b2, nullptr, lw, lb, dur);
  k_gather<<<2048, 256, 0, stream>>>(x, idxb, out0);
}

// Round 4
// 134.556 us; speedup vs baseline: 1.2948x; 1.2948x over previous
//
#include <hip/hip_runtime.h>

#define DEV __device__ __forceinline__

typedef unsigned short u16;
typedef __attribute__((ext_vector_type(8))) short bf16x8;   // 8 bf16 (4 VGPRs)
typedef __attribute__((ext_vector_type(8))) unsigned short u16x8;
typedef __attribute__((ext_vector_type(4))) float f32x4;

constexpr int Bz = 32, Lz = 1024, Dz = 384, Fz = 384, KWz = 3, Mz = 4096;
constexpr float EPS = 1e-5f;

DEV u16 f2bf(float f) {  // RNE f32 -> bf16
  unsigned u = __float_as_uint(f);
  u += 0x7fffu + ((u >> 16) & 1u);
  return (u16)(u >> 16);
}

typedef __attribute__((address_space(1))) const unsigned char ga_t;
typedef __attribute__((address_space(3))) unsigned char la_t;
DEV void gload16(const void* g, void* l) {
  // async global->LDS, 16B per lane; LDS dest is wave-uniform base + lane*16
  __builtin_amdgcn_global_load_lds((ga_t*)g, (la_t*)l, 16, 0, 0);
}

// ---- fused: convert x (f32 -> padded bf16 [B][L+2][D]) + weight prep -------
__global__ void k_pre(const float* __restrict__ x, u16* __restrict__ xbf,
                      const float* __restrict__ w1, const float* __restrict__ w2,
                      u16* __restrict__ w1t, u16* __restrict__ w2t,
                      u16* __restrict__ h1) {
  constexpr int CONV_BLKS = (Bz * Lz * Dz / 8) / 256;  // 768
  if (blockIdx.x < CONV_BLKS) {
    int gid = blockIdx.x * 256 + threadIdx.x;
    size_t e = (size_t)gid * 8;
    float4 v0 = *reinterpret_cast<const float4*>(x + e);
    float4 v1 = *reinterpret_cast<const float4*>(x + e + 4);
    int d = (int)(e % Dz);               // 8 | 384 -> never crosses a row
    int l = (int)((e / Dz) % Lz);
    int b = (int)(e / ((size_t)Dz * Lz));
    u16x8 u;
    u[0] = f2bf(v0.x); u[1] = f2bf(v0.y); u[2] = f2bf(v0.z); u[3] = f2bf(v0.w);
    u[4] = f2bf(v1.x); u[5] = f2bf(v1.y); u[6] = f2bf(v1.z); u[7] = f2bf(v1.w);
    *reinterpret_cast<u16x8*>(xbf + ((size_t)(b * (Lz + 2) + l + 1)) * Dz + d) = u;
    return;
  }
  int gid = (blockIdx.x - CONV_BLKS) * 256 + threadIdx.x;
  constexpr int WT = KWz * Fz * Dz;  // 442368
  if (gid < WT) {
    int k = gid / (Fz * Dz), rem = gid % (Fz * Dz);
    int f = rem / Dz, d = rem % Dz;
    w1t[gid] = f2bf(w1[(f * Dz + d) * KWz + k]);
  } else if (gid < 2 * WT) {
    int g2 = gid - WT;
    int k = g2 / (Fz * Fz), rem = g2 % (Fz * Fz);
    int co = rem / Fz, ci = rem % Fz;
    w2t[g2] = f2bf(w2[(co * Fz + ci) * KWz + k]);
  } else {
    int p = gid - 2 * WT;
    if (p < 2 * Bz * 2 * Dz) {  // halo rows of xbf and h1
      u16* buf = (p < Bz * 2 * Dz) ? xbf : h1;
      int q = p % (Bz * 2 * Dz);
      int b = q / (2 * Dz), r = (q / Dz) & 1, d = q % Dz;
      size_t row = (size_t)b * (Lz + 2) + (r ? (Lz + 1) : 0);
      buf[row * Dz + d] = 0;
    }
  }
}

// -------- cumsum of durations + searchsorted(right) -> idx per frame --------
__global__ __launch_bounds__(1024) void k_scan(const int* __restrict__ tgt,
                                               int* __restrict__ idxb) {
  __shared__ int sc[Lz];
  int b = blockIdx.x, tid = threadIdx.x;
  sc[tid] = tgt[b * Lz + tid];
  __syncthreads();
  for (int off = 1; off < Lz; off <<= 1) {
    int add = (tid >= off) ? sc[tid - off] : 0;
    __syncthreads();
    sc[tid] += add;
    __syncthreads();
  }
  int total = sc[Lz - 1];
  for (int t = tid; t < Mz; t += 1024) {
    int lo = 0, hi = Lz;
    while (lo < hi) {  // first j with cum[j] > t  (== searchsorted right)
      int mid = (lo + hi) >> 1;
      if (sc[mid] > t) hi = mid; else lo = mid + 1;
    }
    int iv = (t < total) ? (lo > Lz - 1 ? Lz - 1 : lo) : -1;
    idxb[b * Mz + t] = iv;
  }
}

// ------------------------------ gather rows ---------------------------------
__global__ void k_gather(const float* __restrict__ x, const int* __restrict__ idxb,
                         float* __restrict__ out) {
  int wid = (blockIdx.x * blockDim.x + threadIdx.x) >> 6;
  int lane = threadIdx.x & 63;
  int nw = (gridDim.x * blockDim.x) >> 6;
  for (int row = wid; row < Bz * Mz; row += nw) {
    int b = row >> 12;  // Mz = 4096
    int iv = idxb[row];
    float4* dst = reinterpret_cast<float4*>(out + (size_t)row * Dz);
    if (iv < 0) {
      float4 z = make_float4(0.f, 0.f, 0.f, 0.f);
      dst[lane] = z;
      if (lane < 32) dst[64 + lane] = z;
    } else {
      const float4* src =
          reinterpret_cast<const float4*>(x + ((size_t)b * Lz + iv) * Dz);
      dst[lane] = src[lane];
      if (lane < 32) dst[64 + lane] = src[64 + lane];
    }
  }
}

// --------- fused conv1d(K=3,'same') + LayerNorm + ReLU (+ final dot) --------
// GEMM tile: [128 rows] x [384 cols], K = 36 steps of 32. 8 waves (2x4), wave
// tile 64x96. Triple-buffered LDS, counted vmcnt(4) + raw s_barrier: stage
// kt+1 stays in flight across the barrier (T3+T4), 1 barrier/step.
template <int LAYER>
__global__ __launch_bounds__(512, 2) void k_conv(
    const u16* __restrict__ in,    // [Bz][Lz+2][384] bf16 (halo-padded)
    const u16* __restrict__ wt,    // [3][384 out][384 in] bf16
    const float* __restrict__ cbias,
    const float* __restrict__ lng, const float* __restrict__ lnb,
    u16* __restrict__ hout,        // LAYER==1: padded output buffer
    const float* __restrict__ lw, const float* __restrict__ lbias,
    float* __restrict__ dur)       // LAYER==2: [B*L]
{
  __shared__ __align__(16) u16 Ash[3][128 * 32];   // 3 x 8KB
  __shared__ __align__(16) u16 Bsh[3][384 * 32];   // 3 x 24KB
  __shared__ float s_sum[4][128], s_sq[4][128], s_dot[4][128];

  const int tid = threadIdx.x;
  const int lane = tid & 63, wave = tid >> 6;   // 8 waves
  const int wr = wave >> 2, wc = wave & 3;      // 2 x 4 wave grid
  const int l15 = lane & 15, lh = lane >> 4;
  const int b = blockIdx.x >> 3, l0 = (blockIdx.x & 7) << 7;

  // ---- staging: 32 chunks of 1KB (A:0-7, B:8-31), wave w takes w + 8i -----
  const u16* in_row = in + ((size_t)(b * (Lz + 2) + l0)) * 384;
  int gof[4], ldo[4];
  bool isa[4];
  #pragma unroll
  for (int i = 0; i < 4; ++i) {
    int c = wave + 8 * i;
    bool a = (c < 8);
    int cb = a ? c : c - 8;
    int slot = cb * 64 + lane, r = slot >> 2, q = slot & 3;
    int ks = q ^ ((r >> 1) & 3);             // XOR slot swizzle (involution)
    gof[i] = r * 384 + ks * 8;
    ldo[i] = cb * 512;
    isa[i] = a;
  }

  auto STAGE = [&](int kt, int buf) {
    int tap = kt / 12;
    int d0 = (kt - tap * 12) * 32;
    const u16* sa = in_row + tap * 384 + d0;
    const u16* sb = wt + tap * (384 * 384) + d0;
    #pragma unroll
    for (int i = 0; i < 4; ++i) {
      if (isa[i]) gload16(sa + gof[i], &Ash[buf][ldo[i]]);
      else        gload16(sb + gof[i], &Bsh[buf][ldo[i]]);
    }
  };

  // ---- fragment read offsets (u16 units), swizzle ks = lh ^ ((r>>1)&3) ----
  int aoff[4], boff[6];
  #pragma unroll
  for (int m = 0; m < 4; ++m) {
    int r = wr * 64 + m * 16 + l15;
    aoff[m] = r * 32 + (lh ^ ((r >> 1) & 3)) * 8;
  }
  #pragma unroll
  for (int n = 0; n < 6; ++n) {
    int c = wc * 96 + n * 16 + l15;
    boff[n] = c * 32 + (lh ^ ((c >> 1) & 3)) * 8;
  }

  f32x4 acc[4][6] = {};

  STAGE(0, 0);
  STAGE(1, 1);
  int cur = 0;
  for (int kt = 0; kt < 36; ++kt) {
    // stage kt must be landed; stage kt+1 (4 loads/thread) stays in flight
    if (kt < 35) asm volatile("s_waitcnt vmcnt(4)" ::: "memory");
    else         asm volatile("s_waitcnt vmcnt(0)" ::: "memory");
    __builtin_amdgcn_s_barrier();
    __builtin_amdgcn_sched_barrier(0);
    bf16x8 av[4], bv[6];
    #pragma unroll
    for (int m = 0; m < 4; ++m)
      av[m] = *reinterpret_cast<const bf16x8*>(&Ash[cur][aoff[m]]);
    #pragma unroll
    for (int n = 0; n < 6; ++n)
      bv[n] = *reinterpret_cast<const bf16x8*>(&Bsh[cur][boff[n]]);
    if (kt < 34) {
      int nb = cur + 2; if (nb >= 3) nb -= 3;
      STAGE(kt + 2, nb);  // buf last read at step kt-1; barrier-protected
    }
    #pragma unroll
    for (int m = 0; m < 4; ++m)
      #pragma unroll
      for (int n = 0; n < 6; ++n)
        acc[m][n] =
            __builtin_amdgcn_mfma_f32_16x16x32_bf16(av[m], bv[n], acc[m][n], 0, 0, 0);
    cur = (cur == 2) ? 0 : cur + 1;
  }

  // ---- epilogue: bias + LayerNorm(F) + ReLU, then store bf16 or dot(lw) ----
  __syncthreads();
  float gv[6], bvv[6], cbv[6], lwv[6];
  #pragma unroll
  for (int n = 0; n < 6; ++n) {
    int c = wc * 96 + n * 16 + l15;
    gv[n] = lng[c]; bvv[n] = lnb[c]; cbv[n] = cbias[c];
    lwv[n] = (LAYER == 2) ? lw[c] : 0.f;
  }
  #pragma unroll
  for (int m = 0; m < 4; ++m) {
    #pragma unroll
    for (int r = 0; r < 4; ++r) {
      float s = 0.f, q2 = 0.f;
      #pragma unroll
      for (int n = 0; n < 6; ++n) {
        float v = acc[m][n][r] + cbv[n];
        s += v; q2 += v * v;
      }
      #pragma unroll
      for (int off = 1; off < 16; off <<= 1) {
        s += __shfl_xor(s, off);
        q2 += __shfl_xor(q2, off);
      }
      if (l15 == 0) {
        int row = wr * 64 + m * 16 + lh * 4 + r;
        s_sum[wc][row] = s;
        s_sq[wc][row] = q2;
      }
    }
  }
  __syncthreads();
  #pragma unroll
  for (int m = 0; m < 4; ++m) {
    #pragma unroll
    for (int r = 0; r < 4; ++r) {
      int row = wr * 64 + m * 16 + lh * 4 + r;
      float S = 0.f, Q = 0.f;
      #pragma unroll
      for (int w = 0; w < 4; ++w) { S += s_sum[w][row]; Q += s_sq[w][row]; }
      float mean = S * (1.f / 384.f);
      float var = Q * (1.f / 384.f) - mean * mean;
      float rstd = rsqrtf(var + EPS);
      float dotp = 0.f;
      #pragma unroll
      for (int n = 0; n < 6; ++n) {
        float v = acc[m][n][r] + cbv[n];
        float y = fmaxf((v - mean) * rstd * gv[n] + bvv[n], 0.f);
        if constexpr (LAYER == 1) {
          int c = wc * 96 + n * 16 + l15;
          hout[((size_t)(b * (Lz + 2) + l0 + row + 1)) * 384 + c] = f2bf(y);
        } else {
          dotp += y * lwv[n];
        }
      }
      if constexpr (LAYER == 2) {
        #pragma unroll
        for (int off = 1; off < 16; off <<= 1) dotp += __shfl_xor(dotp, off);
        if (l15 == 0) s_dot[wc][row] = dotp;
      }
    }
  }
  if constexpr (LAYER == 2) {
    __syncthreads();
    if (tid < 128) {
      float dsum = lbias[0];
      #pragma unroll
      for (int w = 0; w < 4; ++w) dsum += s_dot[w][tid];
      dur[(size_t)b * Lz + l0 + tid] = fmaxf(dsum, 0.f);
    }
  }
}

extern "C" void kernel_launch(void* const* d_in, const int* in_sizes, int n_in,
                              void* d_out, int out_size, void* d_ws, size_t ws_size,
                              hipStream_t stream) {
  (void)in_sizes; (void)n_in; (void)out_size; (void)ws_size;
  const float* x   = (const float*)d_in[0];
  const int* tgt   = (const int*)d_in[1];
  const float* w1  = (const float*)d_in[3];
  const float* c1b = (const float*)d_in[4];
  const float* g1  = (const float*)d_in[5];
  const float* b1  = (const float*)d_in[6];
  const float* w2  = (const float*)d_in[7];
  const float* c2b = (const float*)d_in[8];
  const float* g2  = (const float*)d_in[9];
  const float* b2  = (const float*)d_in[10];
  const float* lw  = (const float*)d_in[11];
  const float* lb  = (const float*)d_in[12];

  float* out0 = (float*)d_out;
  float* dur  = out0 + (size_t)Bz * Mz * Dz;

  const size_t xbf_n = (size_t)Bz * (Lz + 2) * Dz;  // 12,607,488 bf16
  const size_t wt_n  = (size_t)KWz * Fz * Dz;       // 442,368 bf16
  u16* xbf = (u16*)d_ws;
  u16* h1  = xbf + xbf_n;
  u16* w1t = h1 + xbf_n;
  u16* w2t = w1t + wt_n;
  int* idxb = (int*)(w2t + wt_n);  // byte offset divisible by 4

  constexpr int CONV_BLKS = (Bz * Lz * Dz / 8) / 256;           // 768
  constexpr int PREP_BLKS = (2 * KWz * Fz * Dz + 2 * Bz * 2 * Dz + 255) / 256;
  k_pre<<<CONV_BLKS + PREP_BLKS, 256, 0, stream>>>(x, xbf, w1, w2, w1t, w2t, h1);
  k_scan<<<Bz, 1024, 0, stream>>>(tgt, idxb);
  k_conv<1><<<256, 512, 0, stream>>>(xbf, w1t, c1b, g1, b1, h1, nullptr, nullptr,
                                     nullptr);
  k_conv<2><<<256, 512, 0, stream>>>(h1, w2t, c2b, g2, b2, nullptr, lw, lb, dur);
  k_gather<<<2048, 256, 0, stream>>>(x, idxb, out0);
}